// Round 6
// baseline (1166.832 us; speedup 1.0000x reference)
//
#include <hip/hip_runtime.h>

#define G    256
#define CCH  16
#define HIDN 128
#define TS   16
#define LDSW 19   // padded LDS row stride (18 used), breaks bank aliasing
#define CSTRIDE (18 * LDSW)
#define XS_FLOATS (CCH * CSTRIDE)     // 5472 floats (21.9 KB)

// ---------------- Kernel 0: transpose w2 [C][HIDN] -> w2t [HIDN][C] ----------------
// w2t row k = ONE contiguous 64B line for the scalar pipe.
__global__ void w2_transpose(const float* __restrict__ w2, float* __restrict__ w2t)
{
    const int i = threadIdx.x;
    for (int j = i; j < CCH * HIDN; j += 256) {
        int c = j >> 7, k = j & 127;      // w2 is [C][HIDN]
        w2t[k * CCH + c] = w2[j];
    }
}

// ---------------- Kernel 1: conv + MLP + residual + pre_life ----------------
// 2 px/thread, 128-thread blocks, SAME 16x16 tile (21.9 KB LDS -> 7 blocks/CU).
// Rationale (R5 model): per k the weight fetch costs ~900cy of serialized K$
// line-fills on EVERY pipe (scalar/LDS/VMEM all measured R2-R5). Only fix:
// amortize - 256cy of FMA per fetch instead of 128. All-scalar weight stream
// (no ds/s_load lgkmcnt mixing - that was R3's confound).
__global__ __launch_bounds__(128) void nca_compute(
    const float* __restrict__ x, const float* __restrict__ w1,
    const float* __restrict__ b1, const float* __restrict__ w2t,
    const float* __restrict__ um, float* __restrict__ out,
    float* __restrict__ alpha_new)
{
    __shared__ __align__(16) float lds[XS_FLOATS];
    const int tx = threadIdx.x, ty = threadIdx.y;       // block = (16, 8)
    const int bx = blockIdx.x * TS, by = blockIdx.y * TS, b = blockIdx.z;
    const int tid = ty * TS + tx;

    // ---- stage 18x18 halo tile of all 16 channels (zero-pad OOB) ----
    const float* xb = x + (size_t)b * CCH * G * G;
    for (int i = tid; i < CCH * 18 * 18; i += 128) {
        int c   = i / (18 * 18);
        int rem = i % (18 * 18);
        int r   = rem / 18;
        int col = rem % 18;
        int gy = by + r - 1, gx = bx + col - 1;
        float v = 0.f;
        if (gy >= 0 && gy < G && gx >= 0 && gx < G)
            v = xb[(size_t)c * G * G + (size_t)gy * G + gx];
        lds[c * CSTRIDE + r * LDSW + col] = v;
    }
    __syncthreads();

    // ---- update-mask loads early ----
    const int gy0 = by + ty, gy1 = by + ty + 8, gx0 = bx + tx;
    const float m0 = um[(size_t)b * G * G + (size_t)gy0 * G + gx0];
    const float m1 = um[(size_t)b * G * G + (size_t)gy1 * G + gx0];

    // ---- perception y[2][48] for rows ty and ty+8 ----
    float y0[48], y1[48];
    #pragma unroll
    for (int c = 0; c < CCH; c++) {
        #pragma unroll
        for (int px = 0; px < 2; px++) {
            const int ry = ty + px * 8;
            const float* xc = &lds[c * CSTRIDE + ry * LDSW + tx];
            float a00 = xc[0],        a01 = xc[1],            a02 = xc[2];
            float a10 = xc[LDSW],     a11 = xc[LDSW + 1],     a12 = xc[LDSW + 2];
            float a20 = xc[2 * LDSW], a21 = xc[2 * LDSW + 1], a22 = xc[2 * LDSW + 2];
            float* y = px ? y1 : y0;
            y[3 * c]     = a11;
            y[3 * c + 1] = ((a02 - a00) + 2.f * (a12 - a10) + (a22 - a20)) * 0.125f;
            y[3 * c + 2] = ((a20 - a00) + 2.f * (a21 - a01) + (a22 - a02)) * 0.125f;
        }
    }

    // ---- pre_life per pixel: 3x3 maxpool of alpha (ch 3) ----
    bool pre[2];
    #pragma unroll
    for (int px = 0; px < 2; px++) {
        const float* xa = &lds[3 * CSTRIDE + (ty + px * 8) * LDSW + tx];
        float mp = -1e30f;
        #pragma unroll
        for (int dy = 0; dy < 3; dy++)
            #pragma unroll
            for (int dx = 0; dx < 3; dx++)
                mp = fmaxf(mp, xa[dy * LDSW + dx]);
        pre[px] = mp > 0.1f;
    }

    float acc0[CCH], acc1[CCH];
    #pragma unroll
    for (int c = 0; c < CCH; c++) { acc0[c] = 0.f; acc1[c] = 0.f; }

    // ---- MLP: per k, 128 FMA (2 px) vs 4 contiguous scalar line-fills ----
    #pragma unroll 2
    for (int k = 0; k < HIDN; k++) {
        const float4* w1r = (const float4*)(w1 + k * 48);    // 3 lines, uniform
        const float4* w2r = (const float4*)(w2t + k * CCH);  // 1 line, uniform
        const float bk = b1[k];
        float h0a = bk, h0b = 0.f, h0c = 0.f, h0d = 0.f;
        float h1a = bk, h1b = 0.f, h1c = 0.f, h1d = 0.f;
        #pragma unroll
        for (int q = 0; q < 12; q++) {
            float4 w = w1r[q];
            h0a = fmaf(w.x, y0[4 * q    ], h0a);
            h0b = fmaf(w.y, y0[4 * q + 1], h0b);
            h0c = fmaf(w.z, y0[4 * q + 2], h0c);
            h0d = fmaf(w.w, y0[4 * q + 3], h0d);
            h1a = fmaf(w.x, y1[4 * q    ], h1a);
            h1b = fmaf(w.y, y1[4 * q + 1], h1b);
            h1c = fmaf(w.z, y1[4 * q + 2], h1c);
            h1d = fmaf(w.w, y1[4 * q + 3], h1d);
        }
        const float hk0 = fmaxf((h0a + h0b) + (h0c + h0d), 0.f);
        const float hk1 = fmaxf((h1a + h1b) + (h1c + h1d), 0.f);
        #pragma unroll
        for (int q = 0; q < 4; q++) {
            float4 w = w2r[q];
            acc0[4 * q    ] = fmaf(w.x, hk0, acc0[4 * q    ]);
            acc0[4 * q + 1] = fmaf(w.y, hk0, acc0[4 * q + 1]);
            acc0[4 * q + 2] = fmaf(w.z, hk0, acc0[4 * q + 2]);
            acc0[4 * q + 3] = fmaf(w.w, hk0, acc0[4 * q + 3]);
            acc1[4 * q    ] = fmaf(w.x, hk1, acc1[4 * q    ]);
            acc1[4 * q + 1] = fmaf(w.y, hk1, acc1[4 * q + 1]);
            acc1[4 * q + 2] = fmaf(w.z, hk1, acc1[4 * q + 2]);
            acc1[4 * q + 3] = fmaf(w.w, hk1, acc1[4 * q + 3]);
        }
    }

    // ---- epilogue: residual (center = y[3c]), pre_life, pristine alpha ----
    #pragma unroll
    for (int px = 0; px < 2; px++) {
        const int gy = (px == 0) ? gy0 : gy1;
        const float m = (px == 0) ? m0 : m1;
        const float* y = px ? y1 : y0;
        const float* acc = px ? acc1 : acc0;
        const size_t pix   = (size_t)gy * G + gx0;
        const size_t obase = (size_t)b * CCH * G * G + pix;
        #pragma unroll
        for (int c = 0; c < CCH; c++) {
            float xn = y[3 * c] + acc[c] * m;
            if (c == 3) alpha_new[(size_t)b * G * G + pix] = xn;  // pre-mask copy
            out[obase + (size_t)c * G * G] = pre[px] ? xn : 0.f;
        }
    }
}

// ---------------- Kernel 2: post_life mask ----------------
// 32x32 tile per block (2048 blocks). Separable 3x3 maxpool via LDS row-max.
// Re-zeroing pre-dead pixels is idempotent (life = pre & post) -> only
// alpha_new is read.
__global__ __launch_bounds__(256) void nca_mask(
    const float* __restrict__ alpha_new, float* __restrict__ out)
{
    __shared__ float na[34 * 36];   // halo alpha, padded stride
    __shared__ float rm[34 * 33];   // horizontal 3-max
    const int tx = threadIdx.x, ty = threadIdx.y;
    const int bx = blockIdx.x * 32, by = blockIdx.y * 32, b = blockIdx.z;
    const int tid = ty * 16 + tx;

    const float* nb = alpha_new + (size_t)b * G * G;
    for (int i = tid; i < 34 * 34; i += 256) {
        int r = i / 34, c = i % 34;
        int gy = by + r - 1, gx = bx + c - 1;
        float v = -1e30f;
        if (gy >= 0 && gy < G && gx >= 0 && gx < G)
            v = nb[(size_t)gy * G + gx];
        na[r * 36 + c] = v;
    }
    __syncthreads();

    for (int i = tid; i < 34 * 32; i += 256) {
        int r = i / 32, c = i % 32;
        const float* p = &na[r * 36 + c];
        rm[r * 33 + c] = fmaxf(fmaxf(p[0], p[1]), p[2]);
    }
    __syncthreads();

    #pragma unroll
    for (int jr = 0; jr < 2; jr++) {
        #pragma unroll
        for (int jc = 0; jc < 2; jc++) {
            const int pr = ty + 16 * jr, pc = tx + 16 * jc;
            float pooled = fmaxf(fmaxf(rm[pr * 33 + pc], rm[(pr + 1) * 33 + pc]),
                                 rm[(pr + 2) * 33 + pc]);
            if (!(pooled > 0.1f)) {
                const size_t obase = (size_t)b * CCH * G * G
                                   + (size_t)(by + pr) * G + (bx + pc);
                #pragma unroll
                for (int c = 0; c < CCH; c++)
                    out[obase + (size_t)c * G * G] = 0.f;
            }
        }
    }
}

extern "C" void kernel_launch(void* const* d_in, const int* in_sizes, int n_in,
                              void* d_out, int out_size, void* d_ws, size_t ws_size,
                              hipStream_t stream) {
    const float* x  = (const float*)d_in[0];
    const float* w1 = (const float*)d_in[1];
    const float* b1 = (const float*)d_in[2];
    const float* w2 = (const float*)d_in[3];
    const float* um = (const float*)d_in[4];
    float* out = (float*)d_out;

    float* w2t       = (float*)d_ws;               // 2048 floats (8 KB)
    float* alpha_new = (float*)d_ws + 2048;        // B*G*G floats (8.4 MB)

    w2_transpose<<<dim3(1), dim3(256), 0, stream>>>(w2, w2t);

    dim3 gridC(G / TS, G / TS, 32);
    dim3 blockC(TS, 8);                 // 128 threads, 2 px/thread
    nca_compute<<<gridC, blockC, 0, stream>>>(x, w1, b1, w2t, um, out, alpha_new);

    dim3 gridM(G / 32, G / 32, 32);
    dim3 blockM(16, 16);
    nca_mask<<<gridM, blockM, 0, stream>>>(alpha_new, out);
}